// Round 4
// baseline (268.181 us; speedup 1.0000x reference)
//
#include <hip/hip_runtime.h>

#define CAP 64

typedef short bf16x8 __attribute__((ext_vector_type(8)));
typedef float f32x4 __attribute__((ext_vector_type(4)));
typedef unsigned short u16;
typedef unsigned int u32;

__device__ __forceinline__ u16 f32_to_bf16(float f) {
  u32 b = __float_as_uint(f);
  b += 0x7fffu + ((b >> 16) & 1u);  // round to nearest even
  return (u16)(b >> 16);
}

// ---------------------------------------------------------------------------
// K0: X fp32 -> bf16, packed into d_out (dead until mlp overwrites it).
// ---------------------------------------------------------------------------
__global__ void convert_x_kernel(const float* __restrict__ X,
                                 u16* __restrict__ Xb, int n8) {
  int i = blockIdx.x * blockDim.x + threadIdx.x;
  if (i >= n8) return;
  float4 a = ((const float4*)X)[2 * i];
  float4 b = ((const float4*)X)[2 * i + 1];
  int4 o;
  o.x = (int)((u32)f32_to_bf16(a.x) | ((u32)f32_to_bf16(a.y) << 16));
  o.y = (int)((u32)f32_to_bf16(a.z) | ((u32)f32_to_bf16(a.w) << 16));
  o.z = (int)((u32)f32_to_bf16(b.x) | ((u32)f32_to_bf16(b.y) << 16));
  o.w = (int)((u32)f32_to_bf16(b.z) | ((u32)f32_to_bf16(b.w) << 16));
  ((int4*)Xb)[i] = o;
}

// ---------------------------------------------------------------------------
// K1: bucketed adjacency build. 2 edges per thread (int2 coalesced loads),
// 4 independent atomic chains in flight, nontemporal scatter stores (no L2
// write-allocate / RFO on lines we'll never re-read before eviction).
// ---------------------------------------------------------------------------
__global__ void fill_adj_kernel(const int* __restrict__ ra,
                                const int* __restrict__ rb,
                                int* __restrict__ cnt,
                                int* __restrict__ adj,
                                int nedges) {
  int tid = blockIdx.x * blockDim.x + threadIdx.x;
  int e0 = tid * 2;
  if (e0 >= nedges) return;
  bool has1 = (e0 + 1) < nedges;
  int2 av = ((const int2*)ra)[tid];
  int2 bv = ((const int2*)rb)[tid];
  int p0 = atomicAdd(&cnt[av.x], 1);
  int p1 = atomicAdd(&cnt[bv.x], 1);
  int p2 = 0, p3 = 0;
  if (has1) {
    p2 = atomicAdd(&cnt[av.y], 1);
    p3 = atomicAdd(&cnt[bv.y], 1);
  }
  if (p0 < CAP)
    __builtin_nontemporal_store(bv.x, &adj[(size_t)av.x * CAP + p0]);
  if (p1 < CAP)
    __builtin_nontemporal_store(av.x, &adj[(size_t)bv.x * CAP + p1]);
  if (has1) {
    if (p2 < CAP)
      __builtin_nontemporal_store(bv.y, &adj[(size_t)av.y * CAP + p2]);
    if (p3 < CAP)
      __builtin_nontemporal_store(av.y, &adj[(size_t)bv.y * CAP + p3]);
  }
}

// ---------------------------------------------------------------------------
// K2: gather-aggregate over bf16 X. TWO nodes per wave: half-wave (32 lanes)
// per node, lane holds 8 B (4 bf16 feats) via uint2 loads -> half the load
// instructions of the 4B/lane version, 4 KB in flight per wave at unroll-8.
// Indices loaded coalesced (lst[hl], lst[hl+32]) and broadcast via __shfl
// within the half-wave. fp32 accumulate; result written as a bf16 row into
// the node's own adj bucket (fully consumed before the store; disjoint).
// ---------------------------------------------------------------------------
__global__ void gather_agg_kernel(const u16* __restrict__ Xb,
                                  const int* __restrict__ cnt,
                                  int* __restrict__ adj,
                                  int nnodes) {
  int gid = blockIdx.x * blockDim.x + threadIdx.x;
  int wid = gid >> 6;
  int l = gid & 63;
  int half = l >> 5;
  int hl = l & 31;
  int node = wid * 2 + half;
  if (node >= nnodes) return;
  const uint2* Xv = (const uint2*)Xb;  // row = 32 uint2 (256 B)
  const int* lst = adj + (size_t)node * CAP;
  int idx0 = lst[hl];        // positions 0..31
  int idx1 = lst[hl + 32];   // positions 32..63
  int n = cnt[node];
  if (n > CAP) n = CAP;
  uint2 ps = Xv[(size_t)node * 32 + hl];
  float a0 = __uint_as_float(ps.x << 16);
  float a1 = __uint_as_float(ps.x & 0xffff0000u);
  float a2 = __uint_as_float(ps.y << 16);
  float a3 = __uint_as_float(ps.y & 0xffff0000u);
  const int base = half << 5;
  for (int k = 0; k < n; k += 8) {
    uint2 pv[8];
#pragma unroll
    for (int t = 0; t < 8; ++t) {
      int pos = k + t;
      int sel = (pos < 32) ? idx0 : idx1;
      int nb = __shfl(sel, base + (pos & 31));
      pv[t] = (pos < n) ? Xv[(size_t)nb * 32 + hl] : make_uint2(0u, 0u);
    }
#pragma unroll
    for (int t = 0; t < 8; ++t) {
      a0 += __uint_as_float(pv[t].x << 16);
      a1 += __uint_as_float(pv[t].x & 0xffff0000u);
      a2 += __uint_as_float(pv[t].y << 16);
      a3 += __uint_as_float(pv[t].y & 0xffff0000u);
    }
  }
  u32 w0 = (u32)f32_to_bf16(a0) | ((u32)f32_to_bf16(a1) << 16);
  u32 w1 = (u32)f32_to_bf16(a2) | ((u32)f32_to_bf16(a3) << 16);
  ((uint2*)adj)[(size_t)node * 32 + hl] = make_uint2(w0, w1);
}

// ---------------------------------------------------------------------------
// K3: transpose+convert weights fp32 -> bf16 (W^T layout [n][k]) into the
// dead `cnt` region (runs after gather).
// ---------------------------------------------------------------------------
__global__ void convert_w_kernel(const float* __restrict__ Wh,
                                 const float* __restrict__ Wo,
                                 u16* __restrict__ WhT,
                                 u16* __restrict__ WoT) {
  int idx = blockIdx.x * 256 + threadIdx.x;  // 0..32767
  const float* src = (idx < 16384) ? Wh : Wo;
  u16* dst = (idx < 16384) ? WhT : WoT;
  int i = idx & 16383;
  int k = i >> 7, n = i & 127;
  dst[n * 128 + k] = f32_to_bf16(src[k * 128 + n]);
}

// ---------------------------------------------------------------------------
// K4: fused MLP via bf16 MFMA (16x16x32) -- unchanged from round 3.
// ---------------------------------------------------------------------------
__global__ __launch_bounds__(256) void mlp_mfma_kernel(
    const u16* __restrict__ Xagg,  // [nnodes][128] bf16 (lives in adj region)
    const u16* __restrict__ WhT,   // [128][128] bf16, [n][k]
    const u16* __restrict__ WoT,   // [128][128] bf16, [n][k]
    const float* __restrict__ bh,
    const float* __restrict__ bo,
    float* __restrict__ out, int nnodes) {
  __shared__ u16 smem[2 * 128 * 128];  // 64 KB
  u16* sA = smem;
  u16* sW = smem + 16384;

  const int tid = threadIdx.x;
  const int w = tid >> 6;
  const int l = tid & 63;
  const int l15 = l & 15;
  const int l4 = l >> 4;  // quad 0..3
  const int r0 = blockIdx.x * 128;

  // ---- stage sA (Xagg tile) and sW (Wh^T), swizzled 16B units ----
#pragma unroll
  for (int t = 0; t < 8; ++t) {
    int id = tid + t * 256;  // 0..2047 : 128 rows x 16 units
    int r = id >> 4, u = id & 15;
    int gr = r0 + r;
    if (gr >= nnodes) gr = nnodes - 1;
    *(int4*)&sA[r * 128 + ((u ^ (r & 15)) * 8)] =
        *(const int4*)&Xagg[(size_t)gr * 128 + u * 8];
    *(int4*)&sW[r * 128 + ((u ^ (r & 15)) * 8)] =
        *(const int4*)&WhT[r * 128 + u * 8];
  }

  float bhv[8], bov[8];
#pragma unroll
  for (int j = 0; j < 8; ++j) {
    bhv[j] = bh[j * 16 + l15];
    bov[j] = bo[j * 16 + l15];
  }
  __syncthreads();

  const int m0 = w * 32 + l15;       // A row, m-tile 0
  const int m1 = w * 32 + 16 + l15;  // A row, m-tile 1

  f32x4 acc[2][8];
#pragma unroll
  for (int i = 0; i < 2; ++i)
#pragma unroll
    for (int j = 0; j < 8; ++j) acc[i][j] = (f32x4){0.f, 0.f, 0.f, 0.f};

  // ---- GEMM1: hidden = Xagg @ Wh ----
#pragma unroll
  for (int c = 0; c < 4; ++c) {  // K chunks of 32
    int pu = ((c * 4 + l4) ^ l15) * 8;
    bf16x8 a0 = *(bf16x8*)&sA[m0 * 128 + pu];
    bf16x8 a1 = *(bf16x8*)&sA[m1 * 128 + pu];
#pragma unroll
    for (int j = 0; j < 8; ++j) {
      bf16x8 bfr = *(bf16x8*)&sW[(j * 16 + l15) * 128 + pu];
      acc[0][j] = __builtin_amdgcn_mfma_f32_16x16x32_bf16(a0, bfr, acc[0][j], 0, 0, 0);
      acc[1][j] = __builtin_amdgcn_mfma_f32_16x16x32_bf16(a1, bfr, acc[1][j], 0, 0, 0);
    }
  }

  __syncthreads();  // all waves done reading sW (GEMM1)

  // ---- restage sW with Wo^T ----
#pragma unroll
  for (int t = 0; t < 8; ++t) {
    int id = tid + t * 256;
    int r = id >> 4, u = id & 15;
    *(int4*)&sW[r * 128 + ((u ^ (r & 15)) * 8)] =
        *(const int4*)&WoT[r * 128 + u * 8];
  }

  // ---- bias + relu + bf16, write hidden into sA (own rows only) ----
#pragma unroll
  for (int i = 0; i < 2; ++i)
#pragma unroll
    for (int j = 0; j < 8; ++j)
#pragma unroll
      for (int r = 0; r < 4; ++r) {
        int m = w * 32 + i * 16 + l4 * 4 + r;
        float v = fmaxf(acc[i][j][r] + bhv[j], 0.f);
        int k = j * 16 + l15;
        sA[m * 128 + (((k >> 3) ^ (m & 15)) * 8) + (k & 7)] = f32_to_bf16(v);
      }
  __syncthreads();

  // ---- GEMM2: out = hidden @ Wo (reuse acc) ----
#pragma unroll
  for (int i = 0; i < 2; ++i)
#pragma unroll
    for (int j = 0; j < 8; ++j) acc[i][j] = (f32x4){0.f, 0.f, 0.f, 0.f};

#pragma unroll
  for (int c = 0; c < 4; ++c) {
    int pu = ((c * 4 + l4) ^ l15) * 8;
    bf16x8 a0 = *(bf16x8*)&sA[m0 * 128 + pu];
    bf16x8 a1 = *(bf16x8*)&sA[m1 * 128 + pu];
#pragma unroll
    for (int j = 0; j < 8; ++j) {
      bf16x8 bfr = *(bf16x8*)&sW[(j * 16 + l15) * 128 + pu];
      acc[0][j] = __builtin_amdgcn_mfma_f32_16x16x32_bf16(a0, bfr, acc[0][j], 0, 0, 0);
      acc[1][j] = __builtin_amdgcn_mfma_f32_16x16x32_bf16(a1, bfr, acc[1][j], 0, 0, 0);
    }
  }

  __syncthreads();  // everyone done with sA/sW -> reuse as fp32 out stage

  // ---- epilogue: + bo, stage in LDS, coalesced dwordx4 stores ----
  float* sOut = (float*)smem;  // 128 x 128 fp32 = 64 KB
#pragma unroll
  for (int i = 0; i < 2; ++i)
#pragma unroll
    for (int j = 0; j < 8; ++j)
#pragma unroll
      for (int r = 0; r < 4; ++r) {
        int m = w * 32 + i * 16 + l4 * 4 + r;
        sOut[m * 128 + j * 16 + l15] = acc[i][j][r] + bov[j];
      }
  __syncthreads();
#pragma unroll
  for (int t = 0; t < 16; ++t) {
    int id = tid + t * 256;  // 0..4095 float4 units
    int r = id >> 5, u4 = id & 31;
    int gr = r0 + r;
    if (gr < nnodes)
      ((float4*)out)[(size_t)gr * 32 + u4] = ((const float4*)sOut)[id];
  }
}

// ---------------------------------------------------------------------------
extern "C" void kernel_launch(void* const* d_in, const int* in_sizes, int n_in,
                              void* d_out, int out_size, void* d_ws,
                              size_t ws_size, hipStream_t stream) {
  const float* X = (const float*)d_in[0];
  const int* ra = (const int*)d_in[1];
  const int* rb = (const int*)d_in[2];
  const float* Wh = (const float*)d_in[3];
  const float* bh = (const float*)d_in[4];
  const float* Wo = (const float*)d_in[5];
  const float* bo = (const float*)d_in[6];
  float* out = (float*)d_out;

  int nnodes = in_sizes[0] / 128;
  int nedges = in_sizes[1];

  // ws layout: [cnt: nnodes ints | adj: nnodes*CAP ints]
  // Xb (bf16 X) lives in d_out until mlp overwrites it (gather consumed it).
  // After gather: adj holds Xagg bf16 rows; cnt region dead -> WhT/WoT.
  int* cnt = (int*)d_ws;
  int* adj = cnt + nnodes;
  u16* WhT = (u16*)d_ws;
  u16* WoT = WhT + 16384;
  u16* Xb = (u16*)d_out;

  int n8 = nnodes * 16;  // 128 feats / 8 per thread
  hipMemsetAsync(cnt, 0, (size_t)nnodes * 4, stream);
  convert_x_kernel<<<(n8 + 255) / 256, 256, 0, stream>>>(X, Xb, n8);
  int nthreads_fill = (nedges + 1) / 2;
  fill_adj_kernel<<<(nthreads_fill + 255) / 256, 256, 0, stream>>>(
      ra, rb, cnt, adj, nedges);
  int nwaves = (nnodes + 1) / 2;
  gather_agg_kernel<<<(nwaves * 64 + 255) / 256, 256, 0, stream>>>(Xb, cnt,
                                                                   adj, nnodes);
  convert_w_kernel<<<128, 256, 0, stream>>>(Wh, Wo, WhT, WoT);
  mlp_mfma_kernel<<<(nnodes + 127) / 128, 256, 0, stream>>>(
      (const u16*)adj, WhT, WoT, bh, bo, out, nnodes);
}